// Round 1
// baseline (35.567 us; speedup 1.0000x reference)
//
#include <hip/hip_runtime.h>
#include <hip/hip_bf16.h>
#include <math.h>

// QuantumBottle: out = (v^T N_j v + b_j) where v = product state from RY(tanh(z)*pi),
// N_j = sum_w W[j,w] * Re(V^dagger Z_w V), V = fixed 2-layer Rot+CNOT circuit unitary.

#define QB_LATENT 4
#define QB_LAYERS 2

// ---------------- setup kernel: build packed coefficients C[136][4] ----------------
__global__ void qb_setup(const float* __restrict__ qw,   // (2,4,3)
                         const float* __restrict__ W,    // (4,4)
                         float* __restrict__ C)          // 136*4 floats out
{
    __shared__ float Vr[16][16];
    __shared__ float Vi[16][16];
    const int tid = threadIdx.x;

    if (tid < 16) {
        // simulate shared circuit on basis state e_tid -> column tid of V
        float ar[16], ai[16];
        #pragma unroll
        for (int i = 0; i < 16; ++i) { ar[i] = (i == tid) ? 1.0f : 0.0f; ai[i] = 0.0f; }

        for (int l = 0; l < QB_LAYERS; ++l) {
            // Rot(phi, theta, omega) on each wire (wire w <-> bit (3-w))
            for (int w = 0; w < QB_LATENT; ++w) {
                const float phi = qw[(l * QB_LATENT + w) * 3 + 0];
                const float th  = qw[(l * QB_LATENT + w) * 3 + 1];
                const float om  = qw[(l * QB_LATENT + w) * 3 + 2];
                const float ct = cosf(0.5f * th), st = sinf(0.5f * th);
                const float hp = 0.5f * (phi + om), hm = 0.5f * (phi - om);
                const float epr = cosf(hp), epi = -sinf(hp);   // ep = exp(-i(phi+om)/2)
                const float emr = cosf(hm), emi = -sinf(hm);   // em = exp(-i(phi-om)/2)
                // U = [[ep*ct, -conj(em)*st], [em*st, conj(ep)*ct]]
                const float u00r =  epr * ct, u00i =  epi * ct;
                const float u01r = -emr * st, u01i =  emi * st;
                const float u10r =  emr * st, u10i =  emi * st;
                const float u11r =  epr * ct, u11i = -epi * ct;
                const int bit = 1 << (3 - w);
                for (int i = 0; i < 16; ++i) {
                    if (i & bit) continue;
                    const int i1 = i | bit;
                    const float x0r = ar[i],  x0i = ai[i];
                    const float x1r = ar[i1], x1i = ai[i1];
                    ar[i]  = u00r * x0r - u00i * x0i + u01r * x1r - u01i * x1i;
                    ai[i]  = u00r * x0i + u00i * x0r + u01r * x1i + u01i * x1r;
                    ar[i1] = u10r * x0r - u10i * x0i + u11r * x1r - u11i * x1i;
                    ai[i1] = u10r * x0i + u10i * x0r + u11r * x1i + u11i * x1r;
                }
            }
            // CNOT ring: (0,1),(1,2),(2,3),(3,0) — swap amplitudes where control=1
            for (int w = 0; w < QB_LATENT; ++w) {
                const int cb = 1 << (3 - w);
                const int tb = 1 << (3 - ((w + 1) & 3));
                for (int i = 0; i < 16; ++i) {
                    if ((i & cb) && !(i & tb)) {
                        const int i1 = i | tb;
                        float tr = ar[i]; ar[i] = ar[i1]; ar[i1] = tr;
                        float ti = ai[i]; ai[i] = ai[i1]; ai[i1] = ti;
                    }
                }
            }
        }
        #pragma unroll
        for (int i = 0; i < 16; ++i) { Vr[i][tid] = ar[i]; Vi[i][tid] = ai[i]; }
    }
    __syncthreads();

    if (tid < 136) {
        // map linear term id -> (k, kp) with k <= kp, row-major upper triangle
        int k = 0, rem = tid;
        while (rem >= 16 - k) { rem -= 16 - k; ++k; }
        const int kp = k + rem;

        float m0 = 0.f, m1 = 0.f, m2 = 0.f, m3 = 0.f;  // Re(M_w)[k,kp] for w=0..3
        for (int i = 0; i < 16; ++i) {
            const float pr = Vr[i][k] * Vr[i][kp] + Vi[i][k] * Vi[i][kp];
            m0 += ((i >> 3) & 1) ? -pr : pr;
            m1 += ((i >> 2) & 1) ? -pr : pr;
            m2 += ((i >> 1) & 1) ? -pr : pr;
            m3 += ((i >> 0) & 1) ? -pr : pr;
        }
        const float mult = (k == kp) ? 1.0f : 2.0f;
        #pragma unroll
        for (int j = 0; j < 4; ++j) {
            const float cj = W[j * 4 + 0] * m0 + W[j * 4 + 1] * m1 +
                             W[j * 4 + 2] * m2 + W[j * 4 + 3] * m3;
            C[tid * 4 + j] = mult * cj;
        }
    }
}

// ---------------- main kernel: per-sample quadratic forms ----------------
__global__ void __launch_bounds__(256) qb_main(
    const float* __restrict__ z, const float* __restrict__ scale,
    const float* __restrict__ bias, const float* __restrict__ C,
    float* __restrict__ out, int Bn)
{
    __shared__ __align__(16) float sC[136 * 4];
    for (int i = threadIdx.x; i < 136 * 4; i += 256) sC[i] = C[i];
    __syncthreads();

    const int b = blockIdx.x * 256 + threadIdx.x;
    if (b >= Bn) return;

    const float4 zv = reinterpret_cast<const float4*>(z)[b];
    const float hsc = scale[0] * 0.5f;

    float cs[4], sn[4];
    const float zz[4] = {zv.x, zv.y, zv.z, zv.w};
    #pragma unroll
    for (int w = 0; w < 4; ++w) {
        const float x = zz[w];
        const float e = __expf(-2.0f * fabsf(x));
        float t = __fdividef(1.0f - e, 1.0f + e);   // |tanh(x)|
        t = copysignf(t, x);
        __sincosf(t * hsc, &sn[w], &cs[w]);          // half-angle
    }

    const float ab[4] = {cs[0] * cs[1], cs[0] * sn[1], sn[0] * cs[1], sn[0] * sn[1]};
    const float cd[4] = {cs[2] * cs[3], cs[2] * sn[3], sn[2] * cs[3], sn[2] * sn[3]};
    float v[16];
    #pragma unroll
    for (int p = 0; p < 4; ++p)
        #pragma unroll
        for (int q = 0; q < 4; ++q)
            v[p * 4 + q] = ab[p] * cd[q];

    float a0 = bias[0], a1 = bias[1], a2 = bias[2], a3 = bias[3];
    int t = 0;
    #pragma unroll
    for (int k = 0; k < 16; ++k) {
        #pragma unroll
        for (int kp = k; kp < 16; ++kp) {
            const float qv = v[k] * v[kp];
            const float4 cc = reinterpret_cast<const float4*>(sC)[t];
            a0 = fmaf(cc.x, qv, a0);
            a1 = fmaf(cc.y, qv, a1);
            a2 = fmaf(cc.z, qv, a2);
            a3 = fmaf(cc.w, qv, a3);
            ++t;
        }
    }
    reinterpret_cast<float4*>(out)[b] = make_float4(a0, a1, a2, a3);
}

extern "C" void kernel_launch(void* const* d_in, const int* in_sizes, int n_in,
                              void* d_out, int out_size, void* d_ws, size_t ws_size,
                              hipStream_t stream) {
    const float* z  = (const float*)d_in[0];   // (B,4)
    const float* sc = (const float*)d_in[1];   // scalar
    const float* qw = (const float*)d_in[2];   // (2,4,3)
    const float* W  = (const float*)d_in[3];   // (4,4)
    const float* bb = (const float*)d_in[4];   // (4,)
    float* out = (float*)d_out;
    float* C   = (float*)d_ws;                 // 136*4 floats of scratch

    const int Bn = in_sizes[0] / 4;

    hipLaunchKernelGGL(qb_setup, dim3(1), dim3(256), 0, stream, qw, W, C);
    hipLaunchKernelGGL(qb_main, dim3((Bn + 255) / 256), dim3(256), 0, stream,
                       z, sc, bb, C, out, Bn);
}